// Round 18
// baseline (135.559 us; speedup 1.0000x reference)
//
#include <hip/hip_runtime.h>

#define N_TOK 8192
#define IN_DIM 1024
#define OUT_DIM 1024
#define NE 8
#define TILE_SH 12288   // shorts/buffer: A [4 chunks][128 rows][8] + B 2 halves

typedef short short8 __attribute__((ext_vector_type(8)));
typedef float f32x16 __attribute__((ext_vector_type(16)));
typedef ushort ushort4v __attribute__((ext_vector_type(4)));

__device__ __forceinline__ ushort f2bf(float f) {
    union { float f; unsigned u; } v; v.f = f;
    unsigned u = v.u;
    unsigned r = (u + 0x7fffu + ((u >> 16) & 1u)) >> 16;
    return (ushort)r;
}

__device__ __forceinline__ float bf2f(short s) {
    union { unsigned u; float f; } v;
    v.u = ((unsigned)(unsigned short)s) << 16;
    return v.f;
}

__device__ __forceinline__ void gl_lds16(const short* g, short* l) {
    __builtin_amdgcn_global_load_lds(
        (const __attribute__((address_space(1))) unsigned int*)g,
        (__attribute__((address_space(3))) unsigned int*)l, 16, 0, 0);
}

// ---- fused prep (R14 verbatim) ----
__global__ __launch_bounds__(256) void prep(const float* __restrict__ x,
                                            const float* __restrict__ Wg,
                                            const float* __restrict__ bg,
                                            const float* __restrict__ W,
                                            short* __restrict__ xb,
                                            short* __restrict__ wt,
                                            unsigned* __restrict__ choice,
                                            float2* __restrict__ wts) {
    __shared__ ushort tile[32][33];
    int bid = blockIdx.x;
    int t = threadIdx.x;
    if (bid < 512) {
        int wid = t >> 6, lane = t & 63;
        int tok0 = bid * 16 + wid * 4;
        float acc[4][8];
        #pragma unroll
        for (int tk = 0; tk < 4; ++tk)
            #pragma unroll
            for (int e = 0; e < 8; ++e) acc[tk][e] = 0.f;

        #pragma unroll
        for (int it = 0; it < 4; ++it) {
            int j = it * 256 + lane * 4;
            float4 wa[4], wb[4];
            #pragma unroll
            for (int r = 0; r < 4; ++r) {
                wa[r] = *(const float4*)(Wg + (size_t)(j + r) * 8);
                wb[r] = *(const float4*)(Wg + (size_t)(j + r) * 8 + 4);
            }
            #pragma unroll
            for (int tk = 0; tk < 4; ++tk) {
                const float* xr = x + (size_t)(tok0 + tk) * IN_DIM;
                float4 v = *(const float4*)(xr + j);
                ushort4v o;
                o[0] = f2bf(v.x); o[1] = f2bf(v.y); o[2] = f2bf(v.z); o[3] = f2bf(v.w);
                *(ushort4v*)(xb + (size_t)(tok0 + tk) * IN_DIM + j) = o;
                #pragma unroll
                for (int r = 0; r < 4; ++r) {
                    float xv = (r == 0) ? v.x : (r == 1) ? v.y : (r == 2) ? v.z : v.w;
                    acc[tk][0] += xv * wa[r].x; acc[tk][1] += xv * wa[r].y;
                    acc[tk][2] += xv * wa[r].z; acc[tk][3] += xv * wa[r].w;
                    acc[tk][4] += xv * wb[r].x; acc[tk][5] += xv * wb[r].y;
                    acc[tk][6] += xv * wb[r].z; acc[tk][7] += xv * wb[r].w;
                }
            }
        }
        #pragma unroll
        for (int tk = 0; tk < 4; ++tk)
            #pragma unroll
            for (int e = 0; e < 8; ++e)
                #pragma unroll
                for (int off = 32; off; off >>= 1)
                    acc[tk][e] += __shfl_xor(acc[tk][e], off, 64);
        if (lane == 0) {
            #pragma unroll
            for (int tk = 0; tk < 4; ++tk) {
                float s[8];
                #pragma unroll
                for (int e = 0; e < 8; ++e) s[e] = acc[tk][e] + bg[e];
                int i0 = 0;
                #pragma unroll
                for (int e = 1; e < 8; ++e) if (s[e] > s[i0]) i0 = e;
                int i1 = (i0 == 0) ? 1 : 0;
                #pragma unroll
                for (int e = 0; e < 8; ++e) if (e != i0 && s[e] > s[i1]) i1 = e;
                float e0 = 1.f, e1 = __expf(s[i1] - s[i0]);
                float inv = 1.f / (e0 + e1);
                choice[tok0 + tk] = (unsigned)i0 | ((unsigned)i1 << 8);
                wts[tok0 + tk] = make_float2(e0 * inv, e1 * inv);
            }
        }
    } else {
        int id = bid - 512;
        int nt = id & 31, kt = (id >> 5) & 31, e = id >> 10;
        int r = t >> 3;
        int c4 = (t & 7) * 4;
        const float4 v = *(const float4*)(W + (((size_t)e * 1024 + kt * 32 + r) * 1024) + nt * 32 + c4);
        tile[c4 + 0][r] = f2bf(v.x);
        tile[c4 + 1][r] = f2bf(v.y);
        tile[c4 + 2][r] = f2bf(v.z);
        tile[c4 + 3][r] = f2bf(v.w);
        __syncthreads();
        int n = t >> 3, kq = (t & 7) * 4;
        ushort4v o;
        o[0] = tile[n][kq + 0]; o[1] = tile[n][kq + 1];
        o[2] = tile[n][kq + 2]; o[3] = tile[n][kq + 3];
        *(ushort4v*)(wt + (((size_t)e * 1024 + nt * 32 + n) * 1024) + kt * 32 + kq) = o;
    }
}

// ---- bucketing (R14 verbatim) ----
__global__ __launch_bounds__(1024) void bucket(const unsigned* __restrict__ choice,
                                               int* __restrict__ counts,
                                               int* __restrict__ entries,
                                               int* __restrict__ inv0,
                                               int* __restrict__ inv1) {
    int e = blockIdx.x;
    int t = threadIdx.x;
    int wid = t >> 6, lane = t & 63;
    __shared__ int wsum[16];
    unsigned c[8];
    #pragma unroll
    for (int chunk = 0; chunk < 8; ++chunk) c[chunk] = choice[chunk * 1024 + t];
    int base = 0;
    #pragma unroll
    for (int chunk = 0; chunk < 8; ++chunk) {
        int tok = chunk * 1024 + t;
        int which = ((int)(c[chunk] & 255u) == e) ? 0
                  : (((int)((c[chunk] >> 8) & 255u) == e) ? 1 : -1);
        unsigned long long m = __ballot(which >= 0);
        if (lane == 0) wsum[wid] = __popcll(m);
        __syncthreads();
        int woff = base;
        #pragma unroll
        for (int i = 0; i < 16; ++i) if (i < wid) woff += wsum[i];
        int tot = 0;
        #pragma unroll
        for (int i = 0; i < 16; ++i) tot += wsum[i];
        if (which >= 0) {
            int rank = __popcll(m & ((1ull << lane) - 1ull));
            int idx = woff + rank;
            entries[e * N_TOK + idx] = tok;
            if (which == 0) inv0[tok] = idx; else inv1[tok] = idx;
        }
        base += tot;
        __syncthreads();
    }
    if (t == 0) counts[e] = base;
}

// ---- grouped GEMM: 128x256 tile, BK=32, 8 waves (2x4, 64x64 each) using
//      mfma_f32_32x32x16_bf16 (2x FLOP/slot, 15% higher ceiling): per wave
//      8 MFMA + 8 ds_read_b128 per K-tile. CHUNK-MAJOR LDS [chunk][row]:
//      32-row fragment reads are contiguous 512B -> conflict-free, no
//      swizzle; gl_lds dest stays linear (thread t -> chunk t>>7, row t&127).
//      R15 single-barrier 3-ring skeleton, counted vmcnt(3). ----
__global__ __launch_bounds__(512, 4) void moe_gemm(const short* __restrict__ xb,
                                                   const short* __restrict__ wt,
                                                   const float* __restrict__ bias,
                                                   const int* __restrict__ counts,
                                                   const int* __restrict__ entries,
                                                   short* __restrict__ ys) {
    int lin = blockIdx.x;
    int e = lin & 7;
    int inner = lin >> 3;                  // 0..255
    int ct = inner & 3, rt = inner >> 2;   // ct 0..3, rt 0..63
    int cnt = counts[e];
    if (rt * 128 >= cnt) return;
    int rows = min(128, cnt - rt * 128);
    int base_e = 0;
    #pragma unroll
    for (int i = 0; i < NE; ++i) base_e += (i < e) ? counts[i] : 0;

    __shared__ __align__(16) short lds[3 * TILE_SH];   // 72 KiB ring
    __shared__ int tok_sh[128];

    int t = threadIdx.x, wid = t >> 6, lane = t & 63;
    int ebase = e * N_TOK + rt * 128;
    if (t < 128) tok_sh[t] = (t < rows) ? entries[ebase + t] : entries[ebase];
    __syncthreads();

    // ---- staging (3 gl_lds/thread/tile): thread t covers chunk = t>>7,
    // row = t&127 of A, B-half0, B-half1; dst linear = t*8 per section ----
    int srow = t & 127, schunk = t >> 7;
    const short* asrc  = xb + (size_t)tok_sh[srow] * IN_DIM + schunk * 8;
    const short* bsrc0 = wt + ((size_t)e * OUT_DIM + ct * 256 + srow) * IN_DIM + schunk * 8;
    const short* bsrc1 = bsrc0 + (size_t)128 * IN_DIM;
    int dst8 = t * 8;

    // ---- fragment offsets (shorts), chunk-major: A = chunk*1024 + row*8;
    // B = 4096 + half*4096 + chunk*1024 + rowh*8. chunk = ks*2 + (lane>>5). ----
    int wr = wid >> 2, wc = wid & 3;       // 2x4 waves; 64 rows x 64 cols each
    int l31 = lane & 31, lhi = lane >> 5;
    int aoff[2][2], boff[2][2];            // [ks][mi/ni]
    #pragma unroll
    for (int ks = 0; ks < 2; ++ks) {
        int chunk = ks * 2 + lhi;
        #pragma unroll
        for (int mi = 0; mi < 2; ++mi)
            aoff[ks][mi] = chunk * 1024 + (wr * 64 + mi * 32 + l31) * 8;
        #pragma unroll
        for (int ni = 0; ni < 2; ++ni) {
            int rowg = wc * 64 + ni * 32 + l31;
            boff[ks][ni] = 4096 + (rowg >> 7) * 4096 + chunk * 1024 + (rowg & 127) * 8;
        }
    }

    f32x16 acc[2][2];
    #pragma unroll
    for (int mi = 0; mi < 2; ++mi)
        #pragma unroll
        for (int ni = 0; ni < 2; ++ni) acc[mi][ni] = (f32x16)(0.0f);

    short8 caf[2][2], cbf[2][2];           // carried fragments [ks][mi/ni]

#define STAGE(BUF, KT)                                                        \
    {                                                                         \
        short* nb = lds + (BUF) * TILE_SH;                                    \
        int nk = (KT) * 32;                                                   \
        gl_lds16(asrc + nk, nb + dst8);                                       \
        gl_lds16(bsrc0 + nk, nb + 4096 + dst8);                               \
        gl_lds16(bsrc1 + nk, nb + 8192 + dst8);                               \
    }

#define LOADFRAGS(BUF)                                                        \
    {                                                                         \
        const short* Ab = lds + (BUF) * TILE_SH;                              \
        _Pragma("unroll")                                                     \
        for (int ks = 0; ks < 2; ++ks) {                                      \
            _Pragma("unroll")                                                 \
            for (int mi = 0; mi < 2; ++mi)                                    \
                caf[ks][mi] = *(const short8*)(Ab + aoff[ks][mi]);            \
            _Pragma("unroll")                                                 \
            for (int ni = 0; ni < 2; ++ni)                                    \
                cbf[ks][ni] = *(const short8*)(Ab + boff[ks][ni]);            \
        }                                                                     \
    }

// iter t: STAGE(t+2); 8 MFMA on carried frags(t); vmcnt(3) [t+1's 3 loads
// landed, t+2's stay in flight]; BARRIER; sched_barrier (race fix, rule#18);
// tail ds_read frags(t+1). Single barrier safe per R15 proof (3-ring).
#define GITER(NXTBUF, STGBUF, KTN, VN, DO_STAGE, DO_TAIL)                     \
    {                                                                         \
        if (DO_STAGE) STAGE(STGBUF, KTN);                                     \
        _Pragma("unroll")                                                     \
        for (int ks = 0; ks < 2; ++ks)                                        \
            _Pragma("unroll")                                                 \
            for (int mi = 0; mi < 2; ++mi)                                    \
                _Pragma("unroll")                                             \
                for (int ni = 0; ni < 2; ++ni)                                \
                    acc[mi][ni] = __builtin_amdgcn_mfma_f32_32x32x16_bf16(    \
                        caf[ks][mi], cbf[ks][ni], acc[mi][ni], 0, 0, 0);      \
        asm volatile("s_waitcnt vmcnt(" VN ")" ::: "memory");                 \
        __builtin_amdgcn_s_barrier();                                         \
        __builtin_amdgcn_sched_barrier(0);                                    \
        if (DO_TAIL) LOADFRAGS(NXTBUF);                                       \
    }

    STAGE(0, 0);
    STAGE(1, 1);
    asm volatile("s_waitcnt vmcnt(3)" ::: "memory");
    __builtin_amdgcn_s_barrier();
    __builtin_amdgcn_sched_barrier(0);
    LOADFRAGS(0);

    for (int kt = 0; kt < 30; kt += 3) {
        GITER(1, 2, kt + 2, "3", 1, 1);
        GITER(2, 0, kt + 3, "3", 1, 1);
        GITER(0, 1, kt + 4, "3", 1, 1);
    }
    GITER(1, 0, 0, "0", 0, 1);   // t=30: drain, read frags(31)
    GITER(0, 0, 0, "0", 0, 0);   // t=31: final MFMA

#undef GITER
#undef LOADFRAGS
#undef STAGE

    // ---- epilogue: acc -> LDS [128][264] -> coalesced 16B bursts ----
    // C/D layout (m74/m101): col = lane&31, row = (reg&3)+8*(reg>>2)+4*(lane>>5)
    __syncthreads();
    short* ep = lds;                       // 128 x 264 shorts = 66 KiB
    const float* be = bias + (size_t)e * OUT_DIM + ct * 256;
    #pragma unroll
    for (int ni = 0; ni < 2; ++ni) {
        int col = wc * 64 + ni * 32 + l31;
        float bv = be[col];
        #pragma unroll
        for (int mi = 0; mi < 2; ++mi) {
            f32x16 a = acc[mi][ni];
            int rbase = wr * 64 + mi * 32 + 4 * lhi;
            #pragma unroll
            for (int reg = 0; reg < 16; ++reg) {
                int row = rbase + (reg & 3) + 8 * (reg >> 2);
                ep[row * 264 + col] = (short)f2bf(a[reg] + bv);
            }
        }
    }
    __syncthreads();
    #pragma unroll
    for (int k = 0; k < 8; ++k) {
        int f = t + k * 512;               // 0..4095: row = f>>5, chunk = f&31
        int row = f >> 5, cw = f & 31;
        if (row < rows) {
            short8 v = *(const short8*)(ep + row * 264 + cw * 8);
            *(short8*)(ys + ((size_t)(base_e + rt * 128 + row)) * OUT_DIM
                       + ct * 256 + cw * 8) = v;
        }
    }
}

// ---- combine (R14 verbatim) ----
__global__ __launch_bounds__(256) void combine(const short* __restrict__ ys,
                                               const unsigned* __restrict__ choice,
                                               const float2* __restrict__ wts,
                                               const int* __restrict__ inv0,
                                               const int* __restrict__ inv1,
                                               const int* __restrict__ counts,
                                               float* __restrict__ out) {
    __shared__ int bases[8];
    if (threadIdx.x < 8) {
        int s = 0;
        #pragma unroll
        for (int i = 0; i < 8; ++i) s += (i < (int)threadIdx.x) ? counts[i] : 0;
        bases[threadIdx.x] = s;
    }
    __syncthreads();
    int tok = blockIdx.x * 2 + (threadIdx.x >> 7);
    int c8 = (threadIdx.x & 127) * 8;
    unsigned ch = choice[tok];
    float2 w = wts[tok];
    int p0 = bases[ch & 255u] + inv0[tok];
    int p1 = bases[(ch >> 8) & 255u] + inv1[tok];
    short8 a = *(const short8*)(ys + (size_t)p0 * OUT_DIM + c8);
    short8 b = *(const short8*)(ys + (size_t)p1 * OUT_DIM + c8);
    float* op = out + (size_t)tok * OUT_DIM + c8;
    float4 o0, o1;
    o0.x = w.x * bf2f(a[0]) + w.y * bf2f(b[0]);
    o0.y = w.x * bf2f(a[1]) + w.y * bf2f(b[1]);
    o0.z = w.x * bf2f(a[2]) + w.y * bf2f(b[2]);
    o0.w = w.x * bf2f(a[3]) + w.y * bf2f(b[3]);
    o1.x = w.x * bf2f(a[4]) + w.y * bf2f(b[4]);
    o1.y = w.x * bf2f(a[5]) + w.y * bf2f(b[5]);
    o1.z = w.x * bf2f(a[6]) + w.y * bf2f(b[6]);
    o1.w = w.x * bf2f(a[7]) + w.y * bf2f(b[7]);
    *(float4*)op = o0;
    *(float4*)(op + 4) = o1;
}

extern "C" void kernel_launch(void* const* d_in, const int* in_sizes, int n_in,
                              void* d_out, int out_size, void* d_ws, size_t ws_size,
                              hipStream_t stream) {
    const float* x  = (const float*)d_in[0];
    const float* W  = (const float*)d_in[1];
    const float* b  = (const float*)d_in[2];
    const float* Wg = (const float*)d_in[3];
    const float* bg = (const float*)d_in[4];
    float* out = (float*)d_out;

    char* ws = (char*)d_ws;
    short* xb        = (short*)(ws);                     // 16 MiB
    short* wt        = (short*)(ws + 16777216);          // 16 MiB
    unsigned* choice = (unsigned*)(ws + 33554432);       // 32 KiB
    float2* wts      = (float2*)(ws + 33587200);         // 64 KiB
    int* inv0        = (int*)(ws + 33652736);            // 32 KiB
    int* inv1        = (int*)(ws + 33685504);            // 32 KiB
    int* entries     = (int*)(ws + 33718272);            // 256 KiB
    int* counts      = (int*)(ws + 34242560);            // 64 B
    short* ys        = (short*)(ws + 34242624);          // 32 MiB

    prep<<<8704, 256, 0, stream>>>(x, Wg, bg, W, xb, wt, choice, wts);
    bucket<<<8, 1024, 0, stream>>>(choice, counts, entries, inv0, inv1);
    moe_gemm<<<2048, 512, 0, stream>>>(xb, wt, b, counts, entries, ys);
    combine<<<4096, 256, 0, stream>>>(ys, choice, wts, inv0, inv1, counts, out);
}

// Round 19
// 101.050 us; speedup vs baseline: 1.3415x; 1.3415x over previous
//
#include <hip/hip_runtime.h>

#define N_TOK 8192
#define IN_DIM 1024
#define OUT_DIM 1024
#define NE 8
#define TILE_SH 12288           // shorts per ring buffer: A 128x32 + B 256x32

typedef short short8 __attribute__((ext_vector_type(8)));
typedef float f32x4 __attribute__((ext_vector_type(4)));
typedef ushort ushort4v __attribute__((ext_vector_type(4)));

__device__ __forceinline__ ushort f2bf(float f) {
    union { float f; unsigned u; } v; v.f = f;
    unsigned u = v.u;
    unsigned r = (u + 0x7fffu + ((u >> 16) & 1u)) >> 16;
    return (ushort)r;
}

__device__ __forceinline__ float bf2f(short s) {
    union { unsigned u; float f; } v;
    v.u = ((unsigned)(unsigned short)s) << 16;
    return v.f;
}

__device__ __forceinline__ void gl_lds16(const short* g, short* l) {
    __builtin_amdgcn_global_load_lds(
        (const __attribute__((address_space(1))) unsigned int*)g,
        (__attribute__((address_space(3))) unsigned int*)l, 16, 0, 0);
}

// ---- fused prep: blocks 0..511 = gating (4 tok/wave, Wg reused in REGISTERS)
//      + x->bf16; blocks 512..8703 = W transpose ----
__global__ __launch_bounds__(256) void prep(const float* __restrict__ x,
                                            const float* __restrict__ Wg,
                                            const float* __restrict__ bg,
                                            const float* __restrict__ W,
                                            short* __restrict__ xb,
                                            short* __restrict__ wt,
                                            unsigned* __restrict__ choice,
                                            float2* __restrict__ wts) {
    __shared__ ushort tile[32][33];
    int bid = blockIdx.x;
    int t = threadIdx.x;
    if (bid < 512) {
        int wid = t >> 6, lane = t & 63;
        int tok0 = bid * 16 + wid * 4;
        float acc[4][8];
        #pragma unroll
        for (int tk = 0; tk < 4; ++tk)
            #pragma unroll
            for (int e = 0; e < 8; ++e) acc[tk][e] = 0.f;

        #pragma unroll
        for (int it = 0; it < 4; ++it) {
            int j = it * 256 + lane * 4;
            float4 wa[4], wb[4];
            #pragma unroll
            for (int r = 0; r < 4; ++r) {
                wa[r] = *(const float4*)(Wg + (size_t)(j + r) * 8);
                wb[r] = *(const float4*)(Wg + (size_t)(j + r) * 8 + 4);
            }
            #pragma unroll
            for (int tk = 0; tk < 4; ++tk) {
                const float* xr = x + (size_t)(tok0 + tk) * IN_DIM;
                float4 v = *(const float4*)(xr + j);
                ushort4v o;
                o[0] = f2bf(v.x); o[1] = f2bf(v.y); o[2] = f2bf(v.z); o[3] = f2bf(v.w);
                *(ushort4v*)(xb + (size_t)(tok0 + tk) * IN_DIM + j) = o;
                #pragma unroll
                for (int r = 0; r < 4; ++r) {
                    float xv = (r == 0) ? v.x : (r == 1) ? v.y : (r == 2) ? v.z : v.w;
                    acc[tk][0] += xv * wa[r].x; acc[tk][1] += xv * wa[r].y;
                    acc[tk][2] += xv * wa[r].z; acc[tk][3] += xv * wa[r].w;
                    acc[tk][4] += xv * wb[r].x; acc[tk][5] += xv * wb[r].y;
                    acc[tk][6] += xv * wb[r].z; acc[tk][7] += xv * wb[r].w;
                }
            }
        }
        #pragma unroll
        for (int tk = 0; tk < 4; ++tk)
            #pragma unroll
            for (int e = 0; e < 8; ++e)
                #pragma unroll
                for (int off = 32; off; off >>= 1)
                    acc[tk][e] += __shfl_xor(acc[tk][e], off, 64);
        if (lane == 0) {
            #pragma unroll
            for (int tk = 0; tk < 4; ++tk) {
                float s[8];
                #pragma unroll
                for (int e = 0; e < 8; ++e) s[e] = acc[tk][e] + bg[e];
                int i0 = 0;
                #pragma unroll
                for (int e = 1; e < 8; ++e) if (s[e] > s[i0]) i0 = e;
                int i1 = (i0 == 0) ? 1 : 0;
                #pragma unroll
                for (int e = 0; e < 8; ++e) if (e != i0 && s[e] > s[i1]) i1 = e;
                float e0 = 1.f, e1 = __expf(s[i1] - s[i0]);
                float inv = 1.f / (e0 + e1);
                choice[tok0 + tk] = (unsigned)i0 | ((unsigned)i1 << 8);
                wts[tok0 + tk] = make_float2(e0 * inv, e1 * inv);
            }
        }
    } else {
        int id = bid - 512;
        int nt = id & 31, kt = (id >> 5) & 31, e = id >> 10;
        int r = t >> 3;
        int c4 = (t & 7) * 4;
        const float4 v = *(const float4*)(W + (((size_t)e * 1024 + kt * 32 + r) * 1024) + nt * 32 + c4);
        tile[c4 + 0][r] = f2bf(v.x);
        tile[c4 + 1][r] = f2bf(v.y);
        tile[c4 + 2][r] = f2bf(v.z);
        tile[c4 + 3][r] = f2bf(v.w);
        __syncthreads();
        int n = t >> 3, kq = (t & 7) * 4;
        ushort4v o;
        o[0] = tile[n][kq + 0]; o[1] = tile[n][kq + 1];
        o[2] = tile[n][kq + 2]; o[3] = tile[n][kq + 3];
        *(ushort4v*)(wt + (((size_t)e * 1024 + nt * 32 + n) * 1024) + kt * 32 + kq) = o;
    }
}

// ---- bucketing: preloaded chunks, deterministic ballot prefix, no atomics ----
__global__ __launch_bounds__(1024) void bucket(const unsigned* __restrict__ choice,
                                               int* __restrict__ counts,
                                               int* __restrict__ entries,
                                               int* __restrict__ inv0,
                                               int* __restrict__ inv1) {
    int e = blockIdx.x;
    int t = threadIdx.x;
    int wid = t >> 6, lane = t & 63;
    __shared__ int wsum[16];
    unsigned c[8];
    #pragma unroll
    for (int chunk = 0; chunk < 8; ++chunk) c[chunk] = choice[chunk * 1024 + t];
    int base = 0;
    #pragma unroll
    for (int chunk = 0; chunk < 8; ++chunk) {
        int tok = chunk * 1024 + t;
        int which = ((int)(c[chunk] & 255u) == e) ? 0
                  : (((int)((c[chunk] >> 8) & 255u) == e) ? 1 : -1);
        unsigned long long m = __ballot(which >= 0);
        if (lane == 0) wsum[wid] = __popcll(m);
        __syncthreads();
        int woff = base;
        #pragma unroll
        for (int i = 0; i < 16; ++i) if (i < wid) woff += wsum[i];
        int tot = 0;
        #pragma unroll
        for (int i = 0; i < 16; ++i) tot += wsum[i];
        if (which >= 0) {
            int rank = __popcll(m & ((1ull << lane) - 1ull));
            int idx = woff + rank;
            entries[e * N_TOK + idx] = tok;
            if (which == 0) inv0[tok] = idx; else inv1[tok] = idx;
        }
        base += tot;
        __syncthreads();
    }
    if (t == 0) counts[e] = base;
}

// ---- grouped GEMM (R14-proven loop): 128x256 tile, BK=32, 4 waves,
//      3-buffer ring, counted vmcnt(6), register-pipelined frags,
//      sched_barrier(0) after each s_barrier (race fix, rule #18/#19).
//      Grid 768: rt<=24 covers counts up to 3072/expert (26 sigma margin). ----
__global__ __launch_bounds__(256, 2) void moe_gemm(const short* __restrict__ xb,
                                                   const short* __restrict__ wt,
                                                   const float* __restrict__ bias,
                                                   const int* __restrict__ counts,
                                                   const int* __restrict__ entries,
                                                   short* __restrict__ ys) {
    int lin = blockIdx.x;
    int e = lin & 7;
    int inner = lin >> 3;
    int ct = inner & 3, rt = inner >> 2;   // rt 0..23
    int cnt = counts[e];
    if (rt * 128 >= cnt) return;
    int rows = min(128, cnt - rt * 128);
    int base_e = 0;
    #pragma unroll
    for (int i = 0; i < NE; ++i) base_e += (i < e) ? counts[i] : 0;

    __shared__ __align__(16) short lds[3 * TILE_SH];
    __shared__ int tok_sh[128];

    int t = threadIdx.x, wid = t >> 6, lane = t & 63;
    int ebase = e * N_TOK + rt * 128;
    if (t < 128) tok_sh[t] = (t < rows) ? entries[ebase + t] : entries[ebase];
    __syncthreads();

    int chunkoff = (((t & 3) ^ ((t >> 2) & 3)) * 8);
    const short* asrc0 = xb + (size_t)tok_sh[t >> 2] * IN_DIM + chunkoff;
    const short* asrc1 = xb + (size_t)tok_sh[64 + (t >> 2)] * IN_DIM + chunkoff;
    const short* bsrc0 = wt + ((size_t)e * OUT_DIM + ct * 256 + (t >> 2)) * IN_DIM + chunkoff;
    const short* bsrc1 = bsrc0 + (size_t)64 * IN_DIM;
    const short* bsrc2 = bsrc0 + (size_t)128 * IN_DIM;
    const short* bsrc3 = bsrc0 + (size_t)192 * IN_DIM;
    int dst8 = t * 8;

    int wr = wid >> 1, wc = wid & 1;
    int frow = lane & 15, fslot = lane >> 4;
    int rslot = (fslot ^ (frow & 3)) * 8;
    int aoff[4], boff[8];
    #pragma unroll
    for (int mi = 0; mi < 4; ++mi) aoff[mi] = (wr * 64 + mi * 16 + frow) * 32 + rslot;
    #pragma unroll
    for (int ni = 0; ni < 8; ++ni) boff[ni] = (wc * 128 + ni * 16 + frow) * 32 + rslot;

    f32x4 acc[4][8];
    #pragma unroll
    for (int mi = 0; mi < 4; ++mi)
        #pragma unroll
        for (int ni = 0; ni < 8; ++ni) acc[mi][ni] = (f32x4)(0.0f);

    short8 caf[4], cbf[8];

#define STAGE(BUF, KT)                                                        \
    {                                                                         \
        short* nb = lds + (BUF) * TILE_SH;                                    \
        int nk = (KT) * 32;                                                   \
        gl_lds16(asrc0 + nk, nb + dst8);                                      \
        gl_lds16(asrc1 + nk, nb + 2048 + dst8);                               \
        gl_lds16(bsrc0 + nk, nb + 4096 + dst8);                               \
        gl_lds16(bsrc1 + nk, nb + 6144 + dst8);                               \
        gl_lds16(bsrc2 + nk, nb + 8192 + dst8);                               \
        gl_lds16(bsrc3 + nk, nb + 10240 + dst8);                              \
    }

#define LOADFRAGS(BUF)                                                        \
    {                                                                         \
        const short* Ab = lds + (BUF) * TILE_SH;                              \
        const short* Bb = Ab + 4096;                                          \
        _Pragma("unroll")                                                     \
        for (int mi = 0; mi < 4; ++mi) caf[mi] = *(const short8*)(Ab + aoff[mi]); \
        _Pragma("unroll")                                                     \
        for (int ni = 0; ni < 8; ++ni) cbf[ni] = *(const short8*)(Bb + boff[ni]); \
        __builtin_amdgcn_sched_barrier(0);                                    \
    }

#define GITER(NXTBUF, STGBUF, KTN, VN, DO_STAGE, DO_TAIL)                     \
    {                                                                         \
        if (DO_STAGE) STAGE(STGBUF, KTN);                                     \
        __builtin_amdgcn_s_barrier();                                         \
        __builtin_amdgcn_s_setprio(1);                                        \
        _Pragma("unroll")                                                     \
        for (int mi = 0; mi < 4; ++mi)                                        \
            _Pragma("unroll")                                                 \
            for (int ni = 0; ni < 8; ++ni)                                    \
                acc[mi][ni] = __builtin_amdgcn_mfma_f32_16x16x32_bf16(        \
                    caf[mi], cbf[ni], acc[mi][ni], 0, 0, 0);                  \
        __builtin_amdgcn_s_setprio(0);                                        \
        asm volatile("s_waitcnt vmcnt(" VN ")" ::: "memory");                 \
        __builtin_amdgcn_s_barrier();                                         \
        __builtin_amdgcn_sched_barrier(0);  /* pin reads AFTER the barrier */ \
        if (DO_TAIL) LOADFRAGS(NXTBUF);                                       \
    }

    STAGE(0, 0);
    STAGE(1, 1);
    asm volatile("s_waitcnt vmcnt(6)" ::: "memory");
    __builtin_amdgcn_s_barrier();
    __builtin_amdgcn_sched_barrier(0);
    LOADFRAGS(0);

    for (int kt = 0; kt < 30; kt += 3) {
        GITER(1, 2, kt + 2, "6", 1, 1);
        GITER(2, 0, kt + 3, "6", 1, 1);
        GITER(0, 1, kt + 4, "6", 1, 1);
    }
    GITER(1, 0, 0, "0", 0, 1);
    GITER(0, 0, 0, "0", 0, 0);

#undef GITER
#undef LOADFRAGS
#undef STAGE

    __syncthreads();
    short* ep = lds;
    const float* be = bias + (size_t)e * OUT_DIM;
    #pragma unroll
    for (int ni = 0; ni < 8; ++ni) {
        int col = wc * 128 + ni * 16 + frow;
        float bv = be[ct * 256 + col];
        #pragma unroll
        for (int mi = 0; mi < 4; ++mi) {
            int rb_ = wr * 64 + mi * 16 + fslot * 4;
            #pragma unroll
            for (int r = 0; r < 4; ++r)
                ep[(rb_ + r) * 268 + col] = (short)f2bf(acc[mi][ni][r] + bv);
        }
    }
    __syncthreads();
    #pragma unroll
    for (int k = 0; k < 16; ++k) {
        int f = t + k * 256;
        int row = f >> 5, cw = f & 31;
        if (row < rows) {
            short8 v = *(const short8*)(ep + row * 268 + cw * 8);
            *(short8*)(ys + ((size_t)(base_e + rt * 128 + row)) * OUT_DIM
                       + ct * 256 + cw * 8) = v;
        }
    }
}

// ---- combine: out[tok] = w0*ys[pos0] + w1*ys[pos1]; 4 tokens/block ----
__global__ __launch_bounds__(256) void combine(const short* __restrict__ ys,
                                               const unsigned* __restrict__ choice,
                                               const float2* __restrict__ wts,
                                               const int* __restrict__ inv0,
                                               const int* __restrict__ inv1,
                                               const int* __restrict__ counts,
                                               float* __restrict__ out) {
    __shared__ int bases[8];
    if (threadIdx.x < 8) {
        int s = 0;
        #pragma unroll
        for (int i = 0; i < 8; ++i) s += (i < (int)threadIdx.x) ? counts[i] : 0;
        bases[threadIdx.x] = s;
    }
    __syncthreads();
    #pragma unroll
    for (int half = 0; half < 2; ++half) {
        int tok = blockIdx.x * 4 + half * 2 + (threadIdx.x >> 7);
        int c8 = (threadIdx.x & 127) * 8;
        unsigned ch = choice[tok];
        float2 w = wts[tok];
        int p0 = bases[ch & 255u] + inv0[tok];
        int p1 = bases[(ch >> 8) & 255u] + inv1[tok];
        short8 a = *(const short8*)(ys + (size_t)p0 * OUT_DIM + c8);
        short8 b = *(const short8*)(ys + (size_t)p1 * OUT_DIM + c8);
        float* op = out + (size_t)tok * OUT_DIM + c8;
        float4 o0, o1;
        o0.x = w.x * bf2f(a[0]) + w.y * bf2f(b[0]);
        o0.y = w.x * bf2f(a[1]) + w.y * bf2f(b[1]);
        o0.z = w.x * bf2f(a[2]) + w.y * bf2f(b[2]);
        o0.w = w.x * bf2f(a[3]) + w.y * bf2f(b[3]);
        o1.x = w.x * bf2f(a[4]) + w.y * bf2f(b[4]);
        o1.y = w.x * bf2f(a[5]) + w.y * bf2f(b[5]);
        o1.z = w.x * bf2f(a[6]) + w.y * bf2f(b[6]);
        o1.w = w.x * bf2f(a[7]) + w.y * bf2f(b[7]);
        *(float4*)op = o0;
        *(float4*)(op + 4) = o1;
    }
}

extern "C" void kernel_launch(void* const* d_in, const int* in_sizes, int n_in,
                              void* d_out, int out_size, void* d_ws, size_t ws_size,
                              hipStream_t stream) {
    const float* x  = (const float*)d_in[0];
    const float* W  = (const float*)d_in[1];
    const float* b  = (const float*)d_in[2];
    const float* Wg = (const float*)d_in[3];
    const float* bg = (const float*)d_in[4];
    float* out = (float*)d_out;

    char* ws = (char*)d_ws;
    short* xb        = (short*)(ws);                     // 16 MiB
    short* wt        = (short*)(ws + 16777216);          // 16 MiB
    unsigned* choice = (unsigned*)(ws + 33554432);       // 32 KiB
    float2* wts      = (float2*)(ws + 33587200);         // 64 KiB
    int* inv0        = (int*)(ws + 33652736);            // 32 KiB
    int* inv1        = (int*)(ws + 33685504);            // 32 KiB
    int* entries     = (int*)(ws + 33718272);            // 256 KiB
    int* counts      = (int*)(ws + 34242560);            // 64 B
    short* ys        = (short*)(ws + 34242624);          // 32 MiB

    prep<<<8704, 256, 0, stream>>>(x, Wg, bg, W, xb, wt, choice, wts);
    bucket<<<8, 1024, 0, stream>>>(choice, counts, entries, inv0, inv1);
    moe_gemm<<<768, 256, 0, stream>>>(xb, wt, b, counts, entries, ys);
    combine<<<2048, 256, 0, stream>>>(ys, choice, wts, inv0, inv1, counts, out);
}

// Round 20
// 100.935 us; speedup vs baseline: 1.3430x; 1.0011x over previous
//
#include <hip/hip_runtime.h>

#define N_TOK 8192
#define IN_DIM 1024
#define OUT_DIM 1024
#define NE 8
#define TILE_SH 12288           // shorts per ring buffer: A 128x32 + B 256x32

typedef short short8 __attribute__((ext_vector_type(8)));
typedef float f32x4 __attribute__((ext_vector_type(4)));
typedef ushort ushort4v __attribute__((ext_vector_type(4)));

__device__ __forceinline__ ushort f2bf(float f) {
    union { float f; unsigned u; } v; v.f = f;
    unsigned u = v.u;
    unsigned r = (u + 0x7fffu + ((u >> 16) & 1u)) >> 16;
    return (ushort)r;
}

__device__ __forceinline__ float bf2f(short s) {
    union { unsigned u; float f; } v;
    v.u = ((unsigned)(unsigned short)s) << 16;
    return v.f;
}

__device__ __forceinline__ void gl_lds16(const short* g, short* l) {
    __builtin_amdgcn_global_load_lds(
        (const __attribute__((address_space(1))) unsigned int*)g,
        (__attribute__((address_space(3))) unsigned int*)l, 16, 0, 0);
}

// ---- fused prep: blocks 0..511 = gating (4 tok/wave, Wg reused in REGISTERS)
//      + x->bf16; blocks 512..1023 = W transpose, one block per (e, 16-row
//      n-slab), full k accumulated in LDS, FULL-ROW coalesced wt writes ----
__global__ __launch_bounds__(256) void prep(const float* __restrict__ x,
                                            const float* __restrict__ Wg,
                                            const float* __restrict__ bg,
                                            const float* __restrict__ W,
                                            short* __restrict__ xb,
                                            short* __restrict__ wt,
                                            unsigned* __restrict__ choice,
                                            float2* __restrict__ wts) {
    __shared__ __align__(16) short big[16 * 1032];   // 33 KiB (transpose branch)
    int bid = blockIdx.x;
    int t = threadIdx.x;
    if (bid < 512) {
        int wid = t >> 6, lane = t & 63;
        int tok0 = bid * 16 + wid * 4;
        float acc[4][8];
        #pragma unroll
        for (int tk = 0; tk < 4; ++tk)
            #pragma unroll
            for (int e = 0; e < 8; ++e) acc[tk][e] = 0.f;

        #pragma unroll
        for (int it = 0; it < 4; ++it) {
            int j = it * 256 + lane * 4;
            float4 wa[4], wb[4];
            #pragma unroll
            for (int r = 0; r < 4; ++r) {
                wa[r] = *(const float4*)(Wg + (size_t)(j + r) * 8);
                wb[r] = *(const float4*)(Wg + (size_t)(j + r) * 8 + 4);
            }
            #pragma unroll
            for (int tk = 0; tk < 4; ++tk) {
                const float* xr = x + (size_t)(tok0 + tk) * IN_DIM;
                float4 v = *(const float4*)(xr + j);
                ushort4v o;
                o[0] = f2bf(v.x); o[1] = f2bf(v.y); o[2] = f2bf(v.z); o[3] = f2bf(v.w);
                *(ushort4v*)(xb + (size_t)(tok0 + tk) * IN_DIM + j) = o;
                #pragma unroll
                for (int r = 0; r < 4; ++r) {
                    float xv = (r == 0) ? v.x : (r == 1) ? v.y : (r == 2) ? v.z : v.w;
                    acc[tk][0] += xv * wa[r].x; acc[tk][1] += xv * wa[r].y;
                    acc[tk][2] += xv * wa[r].z; acc[tk][3] += xv * wa[r].w;
                    acc[tk][4] += xv * wb[r].x; acc[tk][5] += xv * wb[r].y;
                    acc[tk][6] += xv * wb[r].z; acc[tk][7] += xv * wb[r].w;
                }
            }
        }
        #pragma unroll
        for (int tk = 0; tk < 4; ++tk)
            #pragma unroll
            for (int e = 0; e < 8; ++e)
                #pragma unroll
                for (int off = 32; off; off >>= 1)
                    acc[tk][e] += __shfl_xor(acc[tk][e], off, 64);
        if (lane == 0) {
            #pragma unroll
            for (int tk = 0; tk < 4; ++tk) {
                float s[8];
                #pragma unroll
                for (int e = 0; e < 8; ++e) s[e] = acc[tk][e] + bg[e];
                int i0 = 0;
                #pragma unroll
                for (int e = 1; e < 8; ++e) if (s[e] > s[i0]) i0 = e;
                int i1 = (i0 == 0) ? 1 : 0;
                #pragma unroll
                for (int e = 0; e < 8; ++e) if (e != i0 && s[e] > s[i1]) i1 = e;
                float e0 = 1.f, e1 = __expf(s[i1] - s[i0]);
                float inv = 1.f / (e0 + e1);
                choice[tok0 + tk] = (unsigned)i0 | ((unsigned)i1 << 8);
                wts[tok0 + tk] = make_float2(e0 * inv, e1 * inv);
            }
        }
    } else {
        // ---- W [E][K][N] -> Wt [E][N][K] bf16; block = (e, 16-n slab).
        // 16 k-chunks of 64 rows; LDS [16 n][1032 k] (pad 8 -> n-stride is
        // 4 banks, j-writes conflict-light); ONE barrier; full-row writes. ----
        int id = bid - 512;                // 0..511
        int e = id >> 6, nt = id & 63;     // e 0..7, nt 0..63 (16 n each)
        int kr = t >> 2, nj = (t & 3) * 4; // kr 0..63, nj 0,4,8,12
        #pragma unroll
        for (int kt = 0; kt < 16; ++kt) {
            int k = kt * 64 + kr;
            float4 v = *(const float4*)(W + (((size_t)e * 1024 + k) * 1024) + nt * 16 + nj);
            big[(nj + 0) * 1032 + k] = (short)f2bf(v.x);
            big[(nj + 1) * 1032 + k] = (short)f2bf(v.y);
            big[(nj + 2) * 1032 + k] = (short)f2bf(v.z);
            big[(nj + 3) * 1032 + k] = (short)f2bf(v.w);
        }
        __syncthreads();
        // write-out: 16 rows x 1024 shorts = 2048 chunks of 16B; waves write
        // contiguous 1KB bursts within a row -> perfectly coalesced 2KB rows
        #pragma unroll
        for (int it = 0; it < 8; ++it) {
            int f = t + it * 256;          // 0..2047
            int row = f >> 7, cw = f & 127;
            short8 v = *(const short8*)(big + row * 1032 + cw * 8);
            *(short8*)(wt + (((size_t)e * 1024 + nt * 16 + row) * 1024) + cw * 8) = v;
        }
    }
}

// ---- bucketing: preloaded chunks, deterministic ballot prefix, no atomics ----
__global__ __launch_bounds__(1024) void bucket(const unsigned* __restrict__ choice,
                                               int* __restrict__ counts,
                                               int* __restrict__ entries,
                                               int* __restrict__ inv0,
                                               int* __restrict__ inv1) {
    int e = blockIdx.x;
    int t = threadIdx.x;
    int wid = t >> 6, lane = t & 63;
    __shared__ int wsum[16];
    unsigned c[8];
    #pragma unroll
    for (int chunk = 0; chunk < 8; ++chunk) c[chunk] = choice[chunk * 1024 + t];
    int base = 0;
    #pragma unroll
    for (int chunk = 0; chunk < 8; ++chunk) {
        int tok = chunk * 1024 + t;
        int which = ((int)(c[chunk] & 255u) == e) ? 0
                  : (((int)((c[chunk] >> 8) & 255u) == e) ? 1 : -1);
        unsigned long long m = __ballot(which >= 0);
        if (lane == 0) wsum[wid] = __popcll(m);
        __syncthreads();
        int woff = base;
        #pragma unroll
        for (int i = 0; i < 16; ++i) if (i < wid) woff += wsum[i];
        int tot = 0;
        #pragma unroll
        for (int i = 0; i < 16; ++i) tot += wsum[i];
        if (which >= 0) {
            int rank = __popcll(m & ((1ull << lane) - 1ull));
            int idx = woff + rank;
            entries[e * N_TOK + idx] = tok;
            if (which == 0) inv0[tok] = idx; else inv1[tok] = idx;
        }
        base += tot;
        __syncthreads();
    }
    if (t == 0) counts[e] = base;
}

// ---- grouped GEMM (R14/R19-proven loop, byte-identical) ----
__global__ __launch_bounds__(256, 2) void moe_gemm(const short* __restrict__ xb,
                                                   const short* __restrict__ wt,
                                                   const float* __restrict__ bias,
                                                   const int* __restrict__ counts,
                                                   const int* __restrict__ entries,
                                                   short* __restrict__ ys) {
    int lin = blockIdx.x;
    int e = lin & 7;
    int inner = lin >> 3;
    int ct = inner & 3, rt = inner >> 2;   // rt 0..23
    int cnt = counts[e];
    if (rt * 128 >= cnt) return;
    int rows = min(128, cnt - rt * 128);
    int base_e = 0;
    #pragma unroll
    for (int i = 0; i < NE; ++i) base_e += (i < e) ? counts[i] : 0;

    __shared__ __align__(16) short lds[3 * TILE_SH];
    __shared__ int tok_sh[128];

    int t = threadIdx.x, wid = t >> 6, lane = t & 63;
    int ebase = e * N_TOK + rt * 128;
    if (t < 128) tok_sh[t] = (t < rows) ? entries[ebase + t] : entries[ebase];
    __syncthreads();

    int chunkoff = (((t & 3) ^ ((t >> 2) & 3)) * 8);
    const short* asrc0 = xb + (size_t)tok_sh[t >> 2] * IN_DIM + chunkoff;
    const short* asrc1 = xb + (size_t)tok_sh[64 + (t >> 2)] * IN_DIM + chunkoff;
    const short* bsrc0 = wt + ((size_t)e * OUT_DIM + ct * 256 + (t >> 2)) * IN_DIM + chunkoff;
    const short* bsrc1 = bsrc0 + (size_t)64 * IN_DIM;
    const short* bsrc2 = bsrc0 + (size_t)128 * IN_DIM;
    const short* bsrc3 = bsrc0 + (size_t)192 * IN_DIM;
    int dst8 = t * 8;

    int wr = wid >> 1, wc = wid & 1;
    int frow = lane & 15, fslot = lane >> 4;
    int rslot = (fslot ^ (frow & 3)) * 8;
    int aoff[4], boff[8];
    #pragma unroll
    for (int mi = 0; mi < 4; ++mi) aoff[mi] = (wr * 64 + mi * 16 + frow) * 32 + rslot;
    #pragma unroll
    for (int ni = 0; ni < 8; ++ni) boff[ni] = (wc * 128 + ni * 16 + frow) * 32 + rslot;

    f32x4 acc[4][8];
    #pragma unroll
    for (int mi = 0; mi < 4; ++mi)
        #pragma unroll
        for (int ni = 0; ni < 8; ++ni) acc[mi][ni] = (f32x4)(0.0f);

    short8 caf[4], cbf[8];

#define STAGE(BUF, KT)                                                        \
    {                                                                         \
        short* nb = lds + (BUF) * TILE_SH;                                    \
        int nk = (KT) * 32;                                                   \
        gl_lds16(asrc0 + nk, nb + dst8);                                      \
        gl_lds16(asrc1 + nk, nb + 2048 + dst8);                               \
        gl_lds16(bsrc0 + nk, nb + 4096 + dst8);                               \
        gl_lds16(bsrc1 + nk, nb + 6144 + dst8);                               \
        gl_lds16(bsrc2 + nk, nb + 8192 + dst8);                               \
        gl_lds16(bsrc3 + nk, nb + 10240 + dst8);                              \
    }

#define LOADFRAGS(BUF)                                                        \
    {                                                                         \
        const short* Ab = lds + (BUF) * TILE_SH;                              \
        const short* Bb = Ab + 4096;                                          \
        _Pragma("unroll")                                                     \
        for (int mi = 0; mi < 4; ++mi) caf[mi] = *(const short8*)(Ab + aoff[mi]); \
        _Pragma("unroll")                                                     \
        for (int ni = 0; ni < 8; ++ni) cbf[ni] = *(const short8*)(Bb + boff[ni]); \
        __builtin_amdgcn_sched_barrier(0);                                    \
    }

#define GITER(NXTBUF, STGBUF, KTN, VN, DO_STAGE, DO_TAIL)                     \
    {                                                                         \
        if (DO_STAGE) STAGE(STGBUF, KTN);                                     \
        __builtin_amdgcn_s_barrier();                                         \
        __builtin_amdgcn_s_setprio(1);                                        \
        _Pragma("unroll")                                                     \
        for (int mi = 0; mi < 4; ++mi)                                        \
            _Pragma("unroll")                                                 \
            for (int ni = 0; ni < 8; ++ni)                                    \
                acc[mi][ni] = __builtin_amdgcn_mfma_f32_16x16x32_bf16(        \
                    caf[mi], cbf[ni], acc[mi][ni], 0, 0, 0);                  \
        __builtin_amdgcn_s_setprio(0);                                        \
        asm volatile("s_waitcnt vmcnt(" VN ")" ::: "memory");                 \
        __builtin_amdgcn_s_barrier();                                         \
        __builtin_amdgcn_sched_barrier(0);  /* pin reads AFTER the barrier */ \
        if (DO_TAIL) LOADFRAGS(NXTBUF);                                       \
    }

    STAGE(0, 0);
    STAGE(1, 1);
    asm volatile("s_waitcnt vmcnt(6)" ::: "memory");
    __builtin_amdgcn_s_barrier();
    __builtin_amdgcn_sched_barrier(0);
    LOADFRAGS(0);

    for (int kt = 0; kt < 30; kt += 3) {
        GITER(1, 2, kt + 2, "6", 1, 1);
        GITER(2, 0, kt + 3, "6", 1, 1);
        GITER(0, 1, kt + 4, "6", 1, 1);
    }
    GITER(1, 0, 0, "0", 0, 1);
    GITER(0, 0, 0, "0", 0, 0);

#undef GITER
#undef LOADFRAGS
#undef STAGE

    __syncthreads();
    short* ep = lds;
    const float* be = bias + (size_t)e * OUT_DIM;
    #pragma unroll
    for (int ni = 0; ni < 8; ++ni) {
        int col = wc * 128 + ni * 16 + frow;
        float bv = be[ct * 256 + col];
        #pragma unroll
        for (int mi = 0; mi < 4; ++mi) {
            int rb_ = wr * 64 + mi * 16 + fslot * 4;
            #pragma unroll
            for (int r = 0; r < 4; ++r)
                ep[(rb_ + r) * 268 + col] = (short)f2bf(acc[mi][ni][r] + bv);
        }
    }
    __syncthreads();
    #pragma unroll
    for (int k = 0; k < 16; ++k) {
        int f = t + k * 256;
        int row = f >> 5, cw = f & 31;
        if (row < rows) {
            short8 v = *(const short8*)(ep + row * 268 + cw * 8);
            *(short8*)(ys + ((size_t)(base_e + rt * 128 + row)) * OUT_DIM
                       + ct * 256 + cw * 8) = v;
        }
    }
}

// ---- combine: out[tok] = w0*ys[pos0] + w1*ys[pos1]; 4 tokens/block ----
__global__ __launch_bounds__(256) void combine(const short* __restrict__ ys,
                                               const unsigned* __restrict__ choice,
                                               const float2* __restrict__ wts,
                                               const int* __restrict__ inv0,
                                               const int* __restrict__ inv1,
                                               const int* __restrict__ counts,
                                               float* __restrict__ out) {
    __shared__ int bases[8];
    if (threadIdx.x < 8) {
        int s = 0;
        #pragma unroll
        for (int i = 0; i < 8; ++i) s += (i < (int)threadIdx.x) ? counts[i] : 0;
        bases[threadIdx.x] = s;
    }
    __syncthreads();
    #pragma unroll
    for (int half = 0; half < 2; ++half) {
        int tok = blockIdx.x * 4 + half * 2 + (threadIdx.x >> 7);
        int c8 = (threadIdx.x & 127) * 8;
        unsigned ch = choice[tok];
        float2 w = wts[tok];
        int p0 = bases[ch & 255u] + inv0[tok];
        int p1 = bases[(ch >> 8) & 255u] + inv1[tok];
        short8 a = *(const short8*)(ys + (size_t)p0 * OUT_DIM + c8);
        short8 b = *(const short8*)(ys + (size_t)p1 * OUT_DIM + c8);
        float* op = out + (size_t)tok * OUT_DIM + c8;
        float4 o0, o1;
        o0.x = w.x * bf2f(a[0]) + w.y * bf2f(b[0]);
        o0.y = w.x * bf2f(a[1]) + w.y * bf2f(b[1]);
        o0.z = w.x * bf2f(a[2]) + w.y * bf2f(b[2]);
        o0.w = w.x * bf2f(a[3]) + w.y * bf2f(b[3]);
        o1.x = w.x * bf2f(a[4]) + w.y * bf2f(b[4]);
        o1.y = w.x * bf2f(a[5]) + w.y * bf2f(b[5]);
        o1.z = w.x * bf2f(a[6]) + w.y * bf2f(b[6]);
        o1.w = w.x * bf2f(a[7]) + w.y * bf2f(b[7]);
        *(float4*)op = o0;
        *(float4*)(op + 4) = o1;
    }
}

extern "C" void kernel_launch(void* const* d_in, const int* in_sizes, int n_in,
                              void* d_out, int out_size, void* d_ws, size_t ws_size,
                              hipStream_t stream) {
    const float* x  = (const float*)d_in[0];
    const float* W  = (const float*)d_in[1];
    const float* b  = (const float*)d_in[2];
    const float* Wg = (const float*)d_in[3];
    const float* bg = (const float*)d_in[4];
    float* out = (float*)d_out;

    char* ws = (char*)d_ws;
    short* xb        = (short*)(ws);                     // 16 MiB
    short* wt        = (short*)(ws + 16777216);          // 16 MiB
    unsigned* choice = (unsigned*)(ws + 33554432);       // 32 KiB
    float2* wts      = (float2*)(ws + 33587200);         // 64 KiB
    int* inv0        = (int*)(ws + 33652736);            // 32 KiB
    int* inv1        = (int*)(ws + 33685504);            // 32 KiB
    int* entries     = (int*)(ws + 33718272);            // 256 KiB
    int* counts      = (int*)(ws + 34242560);            // 64 B
    short* ys        = (short*)(ws + 34242624);          // 32 MiB

    prep<<<1024, 256, 0, stream>>>(x, Wg, bg, W, xb, wt, choice, wts);
    bucket<<<8, 1024, 0, stream>>>(choice, counts, entries, inv0, inv1);
    moe_gemm<<<768, 256, 0, stream>>>(xb, wt, b, counts, entries, ys);
    combine<<<2048, 256, 0, stream>>>(ys, choice, wts, inv0, inv1, counts, out);
}